// Round 9
// baseline (319.670 us; speedup 1.0000x reference)
//
#include <hip/hip_runtime.h>
#include <stdint.h>

typedef __attribute__((ext_vector_type(8))) short bf16x8;
typedef __attribute__((ext_vector_type(4))) float f32x4;

__device__ __forceinline__ ushort f2bf(float f) {
    union { float f; uint32_t i; } v; v.f = f;
    uint32_t r = v.i + 0x7fff + ((v.i >> 16) & 1);
    return (ushort)(r >> 16);
}
__device__ __forceinline__ uint32_t cvtpk(float lo, float hi) {
    uint32_t r;
    asm("v_cvt_pk_bf16_f32 %0, %1, %2" : "=v"(r) : "v"(lo), "v"(hi));
    return r;
}

typedef unsigned int uint_as1 __attribute__((address_space(1)));
typedef unsigned int uint_as3 __attribute__((address_space(3)));
__device__ __forceinline__ void async16(const void* g, void* l) {
    __builtin_amdgcn_global_load_lds((const uint_as1*)g, (uint_as3*)l, 16, 0, 0);
}

// ---------------- small prep kernels ----------------

__global__ void cvt_f32_bf16(const float* __restrict__ in, ushort* __restrict__ out, int n) {
    int i = blockIdx.x * blockDim.x + threadIdx.x;
    if (i < n) out[i] = f2bf(in[i]);
}

__global__ void prep_bn(const float* __restrict__ bk, const float* __restrict__ gamma,
                        const float* __restrict__ beta, const float* __restrict__ rmean,
                        const float* __restrict__ rvar,
                        float* __restrict__ scaleA, float* __restrict__ shiftA) {
    int i = threadIdx.x;  // 256 threads, 1 block
    float s = gamma[i] * rsqrtf(rvar[i] + 1e-5f);
    scaleA[i] = 0.25f * s;                                // fold Ck^-0.5 = 1/16 as 0.25 per operand
    shiftA[i] = 0.25f * ((bk[i] - rmean[i]) * s + beta[i]);
}

// x [b][512][6400] f32  ->  Xt [b][6400][512] bf16
__global__ void transpose_cvt(const float* __restrict__ x, ushort* __restrict__ xt) {
    __shared__ float t[32][33];
    int b = blockIdx.z;
    int n0 = blockIdx.x * 32, c0 = blockIdx.y * 32;
    const float* xb = x + (size_t)b * 512 * 6400;
    ushort* xtb = xt + (size_t)b * 6400 * 512;
    int tx = threadIdx.x, ty = threadIdx.y;
    t[ty][tx] = xb[(size_t)(c0 + ty) * 6400 + n0 + tx];
    __syncthreads();
    xtb[(size_t)(n0 + ty) * 512 + c0 + tx] = f2bf(t[tx][ty]);
}

// ---------------- unified NT GEMM: C[i][j] = sum_k A[i][k]*B[j][k] ----------------
// Round-6 proven: 128x128 tile, 4 waves, BK=32, 3-buf LDS, counted vmcnt(4) +
// raw s_barrier per K-step. LDS quarter-swizzle (SQ_LDS_BANK_CONFLICT = 0).
// Epilogue repacks acc through LDS for full-line stores; bf16 via v_cvt_pk_bf16_f32.
// EPI 1: bf16 store relu(acc*vec0[col] + vec1[col])   (col-affine, BN+ReLU for Kt)
// EPI 2: bf16 store acc + vec0[row]                   (row bias, V)
// EPI 3: f32  store acc + vec0[row]                   (row bias, final out)
// EPI 5: bf16 store exp(acc); per-row partial sums -> rsum[blockIdx.x*6400+row]
template <int EPI>
__global__ __launch_bounds__(256) void gemm_nt(
    const ushort* __restrict__ A, const ushort* __restrict__ B, void* __restrict__ Cout,
    int K, int lda, int ldb, int ldc,
    size_t zsa, size_t zsb, size_t zsc,
    const float* __restrict__ vec0, const float* __restrict__ vec1,
    float* __restrict__ rsum) {
    // [ A buf0|buf1|buf2 | B buf0|buf1|buf2 ], each 128x32 bf16 = 8 KB; total 48 KB
    __shared__ __align__(16) ushort smem[6 * 4096];

    A += (size_t)blockIdx.z * zsa;
    B += (size_t)blockIdx.z * zsb;

    const int tid = threadIdx.x;
    const int lane = tid & 63, wave = tid >> 6;
    const int wm = wave & 1, wn = wave >> 1;
    const int bM = blockIdx.y * 128, bN = blockIdx.x * 128;

    const int sr = lane >> 2;                              // row 0..15 within 16-row group
    const int scs = ((lane & 3) ^ ((lane >> 3) & 3)) * 8;  // swizzled source quarter
    const ushort* gA0 = A + (size_t)(bM + wave * 32 + sr) * lda + scs;
    const ushort* gA1 = gA0 + (size_t)16 * lda;
    const ushort* gB0 = B + (size_t)(bN + wave * 32 + sr) * ldb + scs;
    const ushort* gB1 = gB0 + (size_t)16 * ldb;
    ushort* lAw = &smem[wave * 1024];              // + buf*4096
    ushort* lBw = &smem[3 * 4096 + wave * 1024];   // + buf*4096

    const int rowA = wm * 64;
    const int rowB = wn * 64;
    const int fr = lane & 15;
    const int fk = ((lane >> 4) ^ ((fr >> 1) & 3)) * 8;   // swizzled quarter read

    f32x4 acc[4][4] = {};
    const int nT = K >> 5;

    auto stage = [&](int t, int buf) {
        const int k0 = t * 32;
        const int ob = buf * 4096;
        async16(gA0 + k0, lAw + ob);
        async16(gA1 + k0, lAw + ob + 512);
        async16(gB0 + k0, lBw + ob);
        async16(gB1 + k0, lBw + ob + 512);
    };

    stage(0, 0);
    if (nT > 1) stage(1, 1);

    for (int t = 0; t < nT; ++t) {
        if (t + 1 < nT) { asm volatile("s_waitcnt vmcnt(4)" ::: "memory"); }
        else            { asm volatile("s_waitcnt vmcnt(0)" ::: "memory"); }
        __builtin_amdgcn_sched_barrier(0);
        __builtin_amdgcn_s_barrier();
        __builtin_amdgcn_sched_barrier(0);
        if (t + 2 < nT) stage(t + 2, (t + 2) % 3);
        const int cur = t % 3;
        const ushort* lA = &smem[cur * 4096];
        const ushort* lB = &smem[3 * 4096 + cur * 4096];
        bf16x8 af[4], bff[4];
#pragma unroll
        for (int mi = 0; mi < 4; mi++)
            af[mi] = *(const bf16x8*)&lA[(rowA + mi * 16 + fr) * 32 + fk];
#pragma unroll
        for (int ni = 0; ni < 4; ni++)
            bff[ni] = *(const bf16x8*)&lB[(rowB + ni * 16 + fr) * 32 + fk];
#pragma unroll
        for (int mi = 0; mi < 4; mi++)
#pragma unroll
            for (int ni = 0; ni < 4; ni++)
                acc[mi][ni] = __builtin_amdgcn_mfma_f32_16x16x32_bf16(af[mi], bff[ni], acc[mi][ni], 0, 0, 0);
        __builtin_amdgcn_sched_barrier(0);
    }
    __builtin_amdgcn_s_barrier();
    __builtin_amdgcn_sched_barrier(0);

    // ---- epilogue: repack through LDS, store full lines ----
    float* Cf = (float*)Cout + (size_t)blockIdx.z * zsc;
    ushort* Cu = (ushort*)Cout + (size_t)blockIdx.z * zsc;
    float* lt = (float*)smem;          // 32*132*4 = 16896 B
    const int g4 = (lane >> 4) * 4;
    const int cl = lane & 15;
    const int lr = tid >> 3;
    const int ch = tid & 7;

#pragma unroll
    for (int mi = 0; mi < 4; ++mi) {
#pragma unroll
        for (int ni = 0; ni < 4; ++ni) {
            const int lcol = wn * 64 + ni * 16 + cl;
#pragma unroll
            for (int r = 0; r < 4; ++r)
                lt[(wm * 16 + g4 + r) * 132 + lcol] = acc[mi][ni][r];
        }
        __syncthreads();
        {
            const int brow = (lr < 16) ? (mi * 16 + lr) : (64 + mi * 16 + (lr - 16));
            const int grow = bM + brow;
            const int gcol = bN + ch * 16;
            float vv[16];
#pragma unroll
            for (int i = 0; i < 16; i += 4) {
                f32x4 q = *(const f32x4*)&lt[lr * 132 + ch * 16 + i];
                vv[i] = q[0]; vv[i + 1] = q[1]; vv[i + 2] = q[2]; vv[i + 3] = q[3];
            }
            if (EPI == 1) {
#pragma unroll
                for (int i = 0; i < 16; i++)
                    vv[i] = fmaxf(vv[i] * vec0[gcol + i] + vec1[gcol + i], 0.f);
            }
            if (EPI == 2 || EPI == 3) {
                const float rb = vec0[grow];
#pragma unroll
                for (int i = 0; i < 16; i++) vv[i] += rb;
            }
            if (EPI == 5) {
                float ssum = 0.f;
#pragma unroll
                for (int i = 0; i < 16; i++) { vv[i] = __expf(vv[i]); ssum += vv[i]; }
                ssum += __shfl_down(ssum, 4, 8);
                ssum += __shfl_down(ssum, 2, 8);
                ssum += __shfl_down(ssum, 1, 8);
                if (ch == 0) rsum[(size_t)blockIdx.x * 6400 + grow] = ssum;
            }
            if (EPI == 3) {
#pragma unroll
                for (int i = 0; i < 16; i += 4) {
                    f32x4 q = { vv[i], vv[i + 1], vv[i + 2], vv[i + 3] };
                    *(f32x4*)&Cf[(size_t)grow * ldc + gcol + i] = q;
                }
            } else {
                uint4 q0 = { cvtpk(vv[0], vv[1]), cvtpk(vv[2], vv[3]),
                             cvtpk(vv[4], vv[5]), cvtpk(vv[6], vv[7]) };
                uint4 q1 = { cvtpk(vv[8], vv[9]), cvtpk(vv[10], vv[11]),
                             cvtpk(vv[12], vv[13]), cvtpk(vv[14], vv[15]) };
                *(uint4*)&Cu[(size_t)grow * ldc + gcol] = q0;
                *(uint4*)&Cu[(size_t)grow * ldc + gcol + 8] = q1;
            }
        }
        __syncthreads();
    }
}

// ---------------- PV GEMM: A (S) streamed HBM->registers, B (V) via LDS ----------------
// Block 128x128, 4 waves, wave tile 32x128 (acc[2][8]); waves own disjoint 32-row
// strips of A so A-fragments load global->reg directly, prefetched 2 tiles ahead
// in named slots (even/odd, hand-unrolled: nT must be even). B: 3-buf LDS, 8KB/buf
// (24 KB total -> high occupancy). One vmcnt(4) per step covers B(t)+A(t):
// queue at wait = [B(t)2 A(t)2 B(t+1)2 A(t+1)2]. f32 store (split-K partials).
__global__ __launch_bounds__(256) void gemm_pv(
    const ushort* __restrict__ A, const ushort* __restrict__ B, float* __restrict__ Cout,
    int K, int lda, int ldb, int ldc,
    size_t zsa, size_t zsb, size_t zsc) {
    __shared__ __align__(16) ushort smem[3 * 4096];   // B bufs only, 24 KB

    A += (size_t)blockIdx.z * zsa;
    B += (size_t)blockIdx.z * zsb;

    const int tid = threadIdx.x;
    const int lane = tid & 63, wave = tid >> 6;
    const int bM = blockIdx.y * 128, bN = blockIdx.x * 128;

    // B staging: per wave 32 rows, swizzled source (round-6 proven scheme)
    const int sr = lane >> 2;
    const int scs = ((lane & 3) ^ ((lane >> 3) & 3)) * 8;
    const ushort* gB0 = B + (size_t)(bN + wave * 32 + sr) * ldb + scs;
    const ushort* gB1 = gB0 + (size_t)16 * ldb;
    ushort* lBw = &smem[wave * 1024];   // + buf*4096

    const int fr = lane & 15;
    const int fq = lane >> 4;
    const int fk = (fq ^ ((fr >> 1) & 3)) * 8;   // swizzled B read

    // A direct: wave owns rows [bM + wave*32, +32); frag mi at +mi*16 rows
    const ushort* gA0 = A + (size_t)(bM + wave * 32 + fr) * lda + fq * 8;
    const ushort* gA1 = gA0 + (size_t)16 * lda;

    f32x4 acc[2][8] = {};
    const int nT = K >> 5;   // must be even (PV: 1280/32 = 40)

    auto stageB = [&](int t, int buf) {
        const int k0 = t * 32;
        const int ob = buf * 4096;
        async16(gB0 + k0, lBw + ob);
        async16(gB1 + k0, lBw + ob + 512);
    };

    // prologue — issue order matters for the vmcnt(4) count: B0 A0 B1 A1
    stageB(0, 0);
    bf16x8 a0E = *(const bf16x8*)&gA0[0];
    bf16x8 a1E = *(const bf16x8*)&gA1[0];
    stageB(1, 1);
    bf16x8 a0O = *(const bf16x8*)&gA0[32];
    bf16x8 a1O = *(const bf16x8*)&gA1[32];

    auto body = [&](int t, bf16x8& a0S, bf16x8& a1S) {
        if (t + 1 < nT) { asm volatile("s_waitcnt vmcnt(4)" ::: "memory"); }
        else            { asm volatile("s_waitcnt vmcnt(0)" ::: "memory"); }
        __builtin_amdgcn_sched_barrier(0);
        __builtin_amdgcn_s_barrier();
        __builtin_amdgcn_sched_barrier(0);
        bf16x8 u0 = a0S, u1 = a1S;        // snapshot before slot reuse
        if (t + 2 < nT) {
            stageB(t + 2, (t + 2) % 3);
            const int k0 = (t + 2) * 32;
            a0S = *(const bf16x8*)&gA0[k0];
            a1S = *(const bf16x8*)&gA1[k0];
        }
        const ushort* lB = &smem[(t % 3) * 4096];
        bf16x8 bff[8];
#pragma unroll
        for (int ni = 0; ni < 8; ni++)
            bff[ni] = *(const bf16x8*)&lB[(ni * 16 + fr) * 32 + fk];
#pragma unroll
        for (int ni = 0; ni < 8; ni++)
            acc[0][ni] = __builtin_amdgcn_mfma_f32_16x16x32_bf16(u0, bff[ni], acc[0][ni], 0, 0, 0);
#pragma unroll
        for (int ni = 0; ni < 8; ni++)
            acc[1][ni] = __builtin_amdgcn_mfma_f32_16x16x32_bf16(u1, bff[ni], acc[1][ni], 0, 0, 0);
        __builtin_amdgcn_sched_barrier(0);
    };

    for (int i = 0; i < nT; i += 2) {
        body(i, a0E, a1E);       // even t: slot E
        body(i + 1, a0O, a1O);   // odd  t: slot O
    }

    // ---- epilogue: 4 wave-phases through LDS, full-line f32 stores ----
    float* Cf = Cout + (size_t)blockIdx.z * zsc;
    float* lt = (float*)smem;    // 32*132*4 = 16896 B <= 24576 B
    const int lr = tid >> 3;     // 0..31
    const int ch = tid & 7;      // 16-col chunk
#pragma unroll
    for (int ph = 0; ph < 4; ++ph) {
        __syncthreads();         // lt free (also drains main-loop LDS reads at ph=0)
        if (wave == ph) {
#pragma unroll
            for (int mi = 0; mi < 2; ++mi)
#pragma unroll
                for (int ni = 0; ni < 8; ++ni)
#pragma unroll
                    for (int r = 0; r < 4; ++r)
                        lt[(mi * 16 + fq * 4 + r) * 132 + ni * 16 + fr] = acc[mi][ni][r];
        }
        __syncthreads();
        const int grow = bM + ph * 32 + lr;
        const int gcol = bN + ch * 16;
#pragma unroll
        for (int i = 0; i < 16; i += 4)
            *(f32x4*)&Cf[(size_t)grow * ldc + gcol + i] = *(const f32x4*)&lt[lr * 132 + ch * 16 + i];
    }
}

// ---------------- softmax normalizer: inv[row] = 1 / sum_xb rsum[xb][row] ----------------
__global__ __launch_bounds__(256) void combine_inv(const float* __restrict__ rsum,
                                                   float* __restrict__ inv) {
    int r = blockIdx.x * 256 + threadIdx.x;   // 6400 rows
    float s = 0.f;
#pragma unroll
    for (int xb = 0; xb < 50; xb++) s += rsum[(size_t)xb * 6400 + r];
    inv[r] = 1.f / s;
}

// ---------------- split-K reduce: ctxT bf16 = inv[row] * sum of 5 f32 partial chunks ----------------
__global__ __launch_bounds__(256) void reduce_ctx(const float* __restrict__ part, ushort* __restrict__ ctx,
                                                  const float* __restrict__ inv) {
    const size_t CH = 1638400;  // elems per chunk
    size_t i = ((size_t)blockIdx.x * 256 + threadIdx.x) * 4;
    float4 a = *(const float4*)&part[i];
#pragma unroll
    for (int c = 1; c < 5; c++) {
        float4 s = *(const float4*)&part[i + (size_t)c * CH];
        a.x += s.x; a.y += s.y; a.z += s.z; a.w += s.w;
    }
    const float w = inv[i >> 8];  // 256 cols per row
    uint2 o = { cvtpk(a.x * w, a.y * w), cvtpk(a.z * w, a.w * w) };
    *(uint2*)&ctx[i] = o;
}

// ---------------- host ----------------
extern "C" void kernel_launch(void* const* d_in, const int* in_sizes, int n_in,
                              void* d_out, int out_size, void* d_ws, size_t ws_size,
                              hipStream_t stream) {
    (void)in_sizes; (void)n_in; (void)out_size; (void)ws_size;
    const float* x     = (const float*)d_in[0];
    const float* wk    = (const float*)d_in[1];
    const float* bk    = (const float*)d_in[2];
    const float* gamma = (const float*)d_in[3];
    const float* beta  = (const float*)d_in[4];
    const float* rmean = (const float*)d_in[5];
    const float* rvar  = (const float*)d_in[6];
    const float* wv    = (const float*)d_in[7];
    const float* bv    = (const float*)d_in[8];
    const float* wW    = (const float*)d_in[9];
    const float* bW    = (const float*)d_in[10];
    float* out = (float*)d_out;

    // workspace layout (ushort elements)
    ushort* Xt   = (ushort*)d_ws;          // 2*6400*512   = 6,553,600
    ushort* wkb  = Xt + 6553600;           // 256*512      = 131,072
    ushort* wvb  = wkb + 131072;           // 131,072
    ushort* wWb  = wvb + 131072;           // 512*256      = 131,072
    ushort* Kt   = wWb + 131072;           // 2*6400*256   = 3,276,800
    ushort* V    = Kt + 3276800;           // 3,276,800
    ushort* ctxT = V + 3276800;            // 3,276,800
    ushort* S    = ctxT + 3276800;         // 6400*6400    = 40,960,000 (one batch, reused)
    float* scaleA = (float*)(S + 40960000);
    float* shiftA = scaleA + 256;
    float* rowsum = shiftA + 256;          // 50*6400      = 320,000 f32
    float* inv    = rowsum + 320000;       // 6400 f32
    float* part   = inv + 6400;            // 5*6400*256 f32 = 8,192,000 f32 (33 MB)
    // total ~150 MB

    cvt_f32_bf16<<<512, 256, 0, stream>>>(wk, wkb, 131072);
    cvt_f32_bf16<<<512, 256, 0, stream>>>(wv, wvb, 131072);
    cvt_f32_bf16<<<512, 256, 0, stream>>>(wW, wWb, 131072);
    prep_bn<<<1, 256, 0, stream>>>(bk, gamma, beta, rmean, rvar, scaleA, shiftA);
    transpose_cvt<<<dim3(200, 16, 2), dim3(32, 32), 0, stream>>>(x, Xt);

    // Kt[b][n][ck] = relu(affine(Xt . wk^T)), scaled by 0.25  — both batches in one dispatch
    gemm_nt<1><<<dim3(2, 50, 2), 256, 0, stream>>>(Xt, wkb, Kt, 512, 512, 512, 256,
                                                   3276800, 0, 1638400, scaleA, shiftA, nullptr);
    // V[b][v][m] = wv . Xt^T + bv
    gemm_nt<2><<<dim3(50, 2, 2), 256, 0, stream>>>(wvb, Xt, V, 512, 512, 512, 6400,
                                                   0, 3276800, 1638400, bv, nullptr, nullptr);

    for (int b = 0; b < 2; b++) {
        ushort* Ktb  = Kt + (size_t)b * 1638400;
        ushort* Vb   = V  + (size_t)b * 1638400;
        ushort* ctxb = ctxT + (size_t)b * 1638400;
        // P_unnorm[n][m] = exp(Kt . Kt^T) (logits already include 1/16); row sums to rowsum
        gemm_nt<5><<<dim3(50, 50), 256, 0, stream>>>(Ktb, Ktb, S, 256, 256, 256, 6400,
                                                     0, 0, 0, nullptr, nullptr, rowsum);
        combine_inv<<<25, 256, 0, stream>>>(rowsum, inv);
        // ctxT[n][v] = P_unnorm . V^T — split-K x5; S->reg direct, V via LDS
        gemm_pv<<<dim3(2, 50, 5), 256, 0, stream>>>(S, Vb, part, 1280, 6400, 6400, 256,
                                                    1280, 1280, 1638400);
        reduce_ctx<<<1600, 256, 0, stream>>>(part, ctxb, inv);
    }

    // out[b][o][n] = wW . ctxT^T + bW  — both batches in one dispatch
    gemm_nt<3><<<dim3(50, 4, 2), 256, 0, stream>>>(wWb, ctxT, out, 256, 256, 256, 6400,
                                                   0, 1638400, 3276800, bW, nullptr, nullptr);
}

// Round 10
// 312.523 us; speedup vs baseline: 1.0229x; 1.0229x over previous
//
#include <hip/hip_runtime.h>
#include <stdint.h>

typedef __attribute__((ext_vector_type(8))) short bf16x8;
typedef __attribute__((ext_vector_type(4))) float f32x4;

__device__ __forceinline__ ushort f2bf(float f) {
    union { float f; uint32_t i; } v; v.f = f;
    uint32_t r = v.i + 0x7fff + ((v.i >> 16) & 1);
    return (ushort)(r >> 16);
}
__device__ __forceinline__ uint32_t cvtpk(float lo, float hi) {
    uint32_t r;
    asm("v_cvt_pk_bf16_f32 %0, %1, %2" : "=v"(r) : "v"(lo), "v"(hi));
    return r;
}

typedef unsigned int uint_as1 __attribute__((address_space(1)));
typedef unsigned int uint_as3 __attribute__((address_space(3)));
__device__ __forceinline__ void async16(const void* g, void* l) {
    __builtin_amdgcn_global_load_lds((const uint_as1*)g, (uint_as3*)l, 16, 0, 0);
}

// ---------------- small prep kernels ----------------

__global__ void cvt_f32_bf16(const float* __restrict__ in, ushort* __restrict__ out, int n) {
    int i = blockIdx.x * blockDim.x + threadIdx.x;
    if (i < n) out[i] = f2bf(in[i]);
}

__global__ void prep_bn(const float* __restrict__ bk, const float* __restrict__ gamma,
                        const float* __restrict__ beta, const float* __restrict__ rmean,
                        const float* __restrict__ rvar,
                        float* __restrict__ scaleA, float* __restrict__ shiftA) {
    int i = threadIdx.x;  // 256 threads, 1 block
    float s = gamma[i] * rsqrtf(rvar[i] + 1e-5f);
    scaleA[i] = 0.25f * s;                                // fold Ck^-0.5 = 1/16 as 0.25 per operand
    shiftA[i] = 0.25f * ((bk[i] - rmean[i]) * s + beta[i]);
}

// x [b][512][6400] f32  ->  Xt [b][6400][512] bf16
__global__ void transpose_cvt(const float* __restrict__ x, ushort* __restrict__ xt) {
    __shared__ float t[32][33];
    int b = blockIdx.z;
    int n0 = blockIdx.x * 32, c0 = blockIdx.y * 32;
    const float* xb = x + (size_t)b * 512 * 6400;
    ushort* xtb = xt + (size_t)b * 6400 * 512;
    int tx = threadIdx.x, ty = threadIdx.y;
    t[ty][tx] = xb[(size_t)(c0 + ty) * 6400 + n0 + tx];
    __syncthreads();
    xtb[(size_t)(n0 + ty) * 512 + c0 + tx] = f2bf(t[tx][ty]);
}

// ---------------- unified NT GEMM (round-6 proven): C[i][j] = sum_k A[i][k]*B[j][k] ----------------
// 128x128 tile, 4 waves, BK=32, 3-buf LDS, counted vmcnt(4) + raw s_barrier.
// LDS quarter-swizzle (SQ_LDS_BANK_CONFLICT = 0). Epilogue repacks via LDS.
// EPI 1: bf16 store relu(acc*vec0[col] + vec1[col]) ; EPI 2: bf16 acc+vec0[row]
// EPI 3: f32 acc+vec0[row]
template <int EPI>
__global__ __launch_bounds__(256) void gemm_nt(
    const ushort* __restrict__ A, const ushort* __restrict__ B, void* __restrict__ Cout,
    int K, int lda, int ldb, int ldc,
    size_t zsa, size_t zsb, size_t zsc,
    const float* __restrict__ vec0, const float* __restrict__ vec1) {
    __shared__ __align__(16) ushort smem[6 * 4096];

    A += (size_t)blockIdx.z * zsa;
    B += (size_t)blockIdx.z * zsb;

    const int tid = threadIdx.x;
    const int lane = tid & 63, wave = tid >> 6;
    const int wm = wave & 1, wn = wave >> 1;
    const int bM = blockIdx.y * 128, bN = blockIdx.x * 128;

    const int sr = lane >> 2;
    const int scs = ((lane & 3) ^ ((lane >> 3) & 3)) * 8;
    const ushort* gA0 = A + (size_t)(bM + wave * 32 + sr) * lda + scs;
    const ushort* gA1 = gA0 + (size_t)16 * lda;
    const ushort* gB0 = B + (size_t)(bN + wave * 32 + sr) * ldb + scs;
    const ushort* gB1 = gB0 + (size_t)16 * ldb;
    ushort* lAw = &smem[wave * 1024];
    ushort* lBw = &smem[3 * 4096 + wave * 1024];

    const int rowA = wm * 64;
    const int rowB = wn * 64;
    const int fr = lane & 15;
    const int fk = ((lane >> 4) ^ ((fr >> 1) & 3)) * 8;

    f32x4 acc[4][4] = {};
    const int nT = K >> 5;

    auto stage = [&](int t, int buf) {
        const int k0 = t * 32;
        const int ob = buf * 4096;
        async16(gA0 + k0, lAw + ob);
        async16(gA1 + k0, lAw + ob + 512);
        async16(gB0 + k0, lBw + ob);
        async16(gB1 + k0, lBw + ob + 512);
    };

    stage(0, 0);
    if (nT > 1) stage(1, 1);

    for (int t = 0; t < nT; ++t) {
        if (t + 1 < nT) { asm volatile("s_waitcnt vmcnt(4)" ::: "memory"); }
        else            { asm volatile("s_waitcnt vmcnt(0)" ::: "memory"); }
        __builtin_amdgcn_sched_barrier(0);
        __builtin_amdgcn_s_barrier();
        __builtin_amdgcn_sched_barrier(0);
        if (t + 2 < nT) stage(t + 2, (t + 2) % 3);
        const int cur = t % 3;
        const ushort* lA = &smem[cur * 4096];
        const ushort* lB = &smem[3 * 4096 + cur * 4096];
        bf16x8 af[4], bff[4];
#pragma unroll
        for (int mi = 0; mi < 4; mi++)
            af[mi] = *(const bf16x8*)&lA[(rowA + mi * 16 + fr) * 32 + fk];
#pragma unroll
        for (int ni = 0; ni < 4; ni++)
            bff[ni] = *(const bf16x8*)&lB[(rowB + ni * 16 + fr) * 32 + fk];
#pragma unroll
        for (int mi = 0; mi < 4; mi++)
#pragma unroll
            for (int ni = 0; ni < 4; ni++)
                acc[mi][ni] = __builtin_amdgcn_mfma_f32_16x16x32_bf16(af[mi], bff[ni], acc[mi][ni], 0, 0, 0);
        __builtin_amdgcn_sched_barrier(0);
    }
    __builtin_amdgcn_s_barrier();
    __builtin_amdgcn_sched_barrier(0);

    float* Cf = (float*)Cout + (size_t)blockIdx.z * zsc;
    ushort* Cu = (ushort*)Cout + (size_t)blockIdx.z * zsc;
    float* lt = (float*)smem;
    const int g4 = (lane >> 4) * 4;
    const int cl = lane & 15;
    const int lr = tid >> 3;
    const int ch = tid & 7;

#pragma unroll
    for (int mi = 0; mi < 4; ++mi) {
#pragma unroll
        for (int ni = 0; ni < 4; ++ni) {
            const int lcol = wn * 64 + ni * 16 + cl;
#pragma unroll
            for (int r = 0; r < 4; ++r)
                lt[(wm * 16 + g4 + r) * 132 + lcol] = acc[mi][ni][r];
        }
        __syncthreads();
        {
            const int brow = (lr < 16) ? (mi * 16 + lr) : (64 + mi * 16 + (lr - 16));
            const int grow = bM + brow;
            const int gcol = bN + ch * 16;
            float vv[16];
#pragma unroll
            for (int i = 0; i < 16; i += 4) {
                f32x4 q = *(const f32x4*)&lt[lr * 132 + ch * 16 + i];
                vv[i] = q[0]; vv[i + 1] = q[1]; vv[i + 2] = q[2]; vv[i + 3] = q[3];
            }
            if (EPI == 1) {
#pragma unroll
                for (int i = 0; i < 16; i++)
                    vv[i] = fmaxf(vv[i] * vec0[gcol + i] + vec1[gcol + i], 0.f);
            }
            if (EPI == 2 || EPI == 3) {
                const float rb = vec0[grow];
#pragma unroll
                for (int i = 0; i < 16; i++) vv[i] += rb;
            }
            if (EPI == 3) {
#pragma unroll
                for (int i = 0; i < 16; i += 4) {
                    f32x4 q = { vv[i], vv[i + 1], vv[i + 2], vv[i + 3] };
                    *(f32x4*)&Cf[(size_t)grow * ldc + gcol + i] = q;
                }
            } else {
                uint4 q0 = { cvtpk(vv[0], vv[1]), cvtpk(vv[2], vv[3]),
                             cvtpk(vv[4], vv[5]), cvtpk(vv[6], vv[7]) };
                uint4 q1 = { cvtpk(vv[8], vv[9]), cvtpk(vv[10], vv[11]),
                             cvtpk(vv[12], vv[13]), cvtpk(vv[14], vv[15]) };
                *(uint4*)&Cu[(size_t)grow * ldc + gcol] = q0;
                *(uint4*)&Cu[(size_t)grow * ldc + gcol + 8] = q1;
            }
        }
        __syncthreads();
    }
}

// ---------------- fused S+PV (flash-style, no S in HBM) ----------------
// Block = (m-chunk mc of 1280, n-block of 128, batch z). Per 128-m-subblock:
//   S   = Kt[n]·Kt[m]^T  (proven 8-step 3-buf loop, swizzled staging)
//   exp = lt-repack -> exp -> rowsum accum -> P bf16 into LDS (quarter-swizzled)
//   PV  = ctx[4][8] += P · V[:,m]^T (4 steps, V tiles 3-buf 16KB, vmcnt(4))
// Outputs: part[mc][n][v] f32 partial ctx; rsum[mc][n] partial row sums.
// LDS: 48KB stage region (6x8KB S slots == 3x16KB V slots == lt) + 32KB P = 80KB.
__global__ __launch_bounds__(256, 2) void fused_spv(
    const ushort* __restrict__ Kt,   // [b][6400][256]
    const ushort* __restrict__ V,    // [b][256][6400]
    float* __restrict__ part,        // [b][5][6400][256]
    float* __restrict__ rsum) {      // [b][5][6400]
    __shared__ __align__(16) ushort smem[40960];   // 80 KB

    const ushort* Ktb = Kt + (size_t)blockIdx.z * 1638400;
    const ushort* Vb  = V  + (size_t)blockIdx.z * 1638400;
    float* partb = part + (size_t)blockIdx.z * 8192000;
    float* rsumb = rsum + (size_t)blockIdx.z * 32000;

    const int tid = threadIdx.x;
    const int lane = tid & 63, wave = tid >> 6;
    const int wm = wave & 1, wn = wave >> 1;
    const int mc = blockIdx.x;           // m-chunk 0..4
    const int bM = blockIdx.y * 128;     // n-rows

    const int sr = lane >> 2;
    const int scs = ((lane & 3) ^ ((lane >> 3) & 3)) * 8;
    const ushort* gA0 = Ktb + (size_t)(bM + wave * 32 + sr) * 256 + scs;   // Kt n-rows (fixed)
    const ushort* gA1 = gA0 + (size_t)16 * 256;
    const ushort* gV  = Vb + (size_t)(wave * 64 + sr) * 6400 + scs;        // V rows (fixed)

    ushort* lAw = &smem[wave * 1024];              // S: A slots, +buf*4096
    ushort* lBw = &smem[3 * 4096 + wave * 1024];   // S: B slots, +buf*4096
    ushort* Pb  = &smem[24576];                    // P: [4 kt][128 row][32]

    const int fr = lane & 15;
    const int fq = lane >> 4;
    const int fk = (fq ^ ((fr >> 1) & 3)) * 8;
    const int rowA = wm * 64, rowB = wn * 64;

    const int g4 = fq * 4;
    const int cl = fr;
    const int lr = tid >> 3;
    const int ch = tid & 7;
    const int brow_r = (lr < 16) ? lr : (64 + lr - 16);   // strip-relative reader row

    f32x4 ctx[4][8] = {};
    float rs0 = 0.f, rs1 = 0.f, rs2 = 0.f, rs3 = 0.f;

#pragma unroll 1
    for (int s = 0; s < 10; ++s) {
        const int m0 = mc * 1280 + s * 128;
        const ushort* gB0 = Ktb + (size_t)(m0 + wave * 32 + sr) * 256 + scs;
        const ushort* gB1 = gB0 + (size_t)16 * 256;

        // ---- S tile: Kt[n]·Kt[m]^T, K=256 ----
        f32x4 sac[4][4] = {};
        auto stage = [&](int t, int buf) {
            const int k0 = t * 32;
            const int ob = buf * 4096;
            async16(gA0 + k0, lAw + ob);
            async16(gA1 + k0, lAw + ob + 512);
            async16(gB0 + k0, lBw + ob);
            async16(gB1 + k0, lBw + ob + 512);
        };
        stage(0, 0);
        stage(1, 1);
        for (int t = 0; t < 8; ++t) {
            if (t < 7) { asm volatile("s_waitcnt vmcnt(4)" ::: "memory"); }
            else       { asm volatile("s_waitcnt vmcnt(0)" ::: "memory"); }
            __builtin_amdgcn_sched_barrier(0);
            __builtin_amdgcn_s_barrier();
            __builtin_amdgcn_sched_barrier(0);
            if (t + 2 < 8) stage(t + 2, (t + 2) % 3);
            const int cur = t % 3;
            const ushort* lA = &smem[cur * 4096];
            const ushort* lB = &smem[3 * 4096 + cur * 4096];
            bf16x8 af[4], bff[4];
#pragma unroll
            for (int mi = 0; mi < 4; mi++)
                af[mi] = *(const bf16x8*)&lA[(rowA + mi * 16 + fr) * 32 + fk];
#pragma unroll
            for (int ni = 0; ni < 4; ni++)
                bff[ni] = *(const bf16x8*)&lB[(rowB + ni * 16 + fr) * 32 + fk];
#pragma unroll
            for (int mi = 0; mi < 4; mi++)
#pragma unroll
                for (int ni = 0; ni < 4; ni++)
                    sac[mi][ni] = __builtin_amdgcn_mfma_f32_16x16x32_bf16(af[mi], bff[ni], sac[mi][ni], 0, 0, 0);
            __builtin_amdgcn_sched_barrier(0);
        }
        __builtin_amdgcn_s_barrier();
        __builtin_amdgcn_sched_barrier(0);

        // ---- exp + rowsum accum + P write (4 strips via lt repack) ----
        {
            float* lt = (float*)smem;   // overlays stage region (S drained)
#pragma unroll
            for (int mi = 0; mi < 4; ++mi) {
#pragma unroll
                for (int ni = 0; ni < 4; ++ni) {
                    const int lcol = wn * 64 + ni * 16 + cl;
#pragma unroll
                    for (int r = 0; r < 4; ++r)
                        lt[(wm * 16 + g4 + r) * 132 + lcol] = sac[mi][ni][r];
                }
                __syncthreads();
                {
                    const int brow = mi * 16 + brow_r;
                    float vv[16];
                    float ss = 0.f;
#pragma unroll
                    for (int i = 0; i < 16; i += 4) {
                        f32x4 q = *(const f32x4*)&lt[lr * 132 + ch * 16 + i];
                        vv[i] = __expf(q[0]); vv[i + 1] = __expf(q[1]);
                        vv[i + 2] = __expf(q[2]); vv[i + 3] = __expf(q[3]);
                        ss += vv[i] + vv[i + 1] + vv[i + 2] + vv[i + 3];
                    }
                    if (mi == 0) rs0 += ss; else if (mi == 1) rs1 += ss;
                    else if (mi == 2) rs2 += ss; else rs3 += ss;
                    // P[kt][brow][quarter q'] = bf16(vv), q' = q ^ ((brow>>1)&3)
                    const int kt = ch >> 1;
                    const int sw = (brow >> 1) & 3;
                    const int q0 = ((ch & 1) * 2) ^ sw;
                    const int q1 = ((ch & 1) * 2 + 1) ^ sw;
                    uint4 pk0 = { cvtpk(vv[0], vv[1]), cvtpk(vv[2], vv[3]),
                                  cvtpk(vv[4], vv[5]), cvtpk(vv[6], vv[7]) };
                    uint4 pk1 = { cvtpk(vv[8], vv[9]), cvtpk(vv[10], vv[11]),
                                  cvtpk(vv[12], vv[13]), cvtpk(vv[14], vv[15]) };
                    *(uint4*)&Pb[kt * 4096 + brow * 32 + q0 * 8] = pk0;
                    *(uint4*)&Pb[kt * 4096 + brow * 32 + q1 * 8] = pk1;
                }
                __syncthreads();
            }
        }

        // ---- PV: ctx += P · V[:, m0..m0+128]^T, K=128, V tiles 16KB 3-buf ----
        auto stageV = [&](int t, int p) {
            const ushort* g = gV + (size_t)(m0 + t * 32);
            ushort* l = &smem[p * 8192 + wave * 2048];
            async16(g, l);
            async16(g + (size_t)16 * 6400, l + 512);
            async16(g + (size_t)32 * 6400, l + 1024);
            async16(g + (size_t)48 * 6400, l + 1536);
        };
        stageV(0, 0);
        stageV(1, 1);
        for (int t = 0; t < 4; ++t) {
            if (t < 3) { asm volatile("s_waitcnt vmcnt(4)" ::: "memory"); }
            else       { asm volatile("s_waitcnt vmcnt(0)" ::: "memory"); }
            __builtin_amdgcn_sched_barrier(0);
            __builtin_amdgcn_s_barrier();
            __builtin_amdgcn_sched_barrier(0);
            if (t + 2 < 4) stageV(t + 2, (t + 2) % 3);
            const ushort* lV = &smem[(t % 3) * 8192];
            bf16x8 pa[4], vf[8];
#pragma unroll
            for (int mi = 0; mi < 4; mi++)
                pa[mi] = *(const bf16x8*)&Pb[t * 4096 + (rowA + mi * 16 + fr) * 32 + fk];
#pragma unroll
            for (int ni = 0; ni < 8; ni++)
                vf[ni] = *(const bf16x8*)&lV[(wn * 128 + ni * 16 + fr) * 32 + fk];
#pragma unroll
            for (int mi = 0; mi < 4; mi++)
#pragma unroll
                for (int ni = 0; ni < 8; ni++)
                    ctx[mi][ni] = __builtin_amdgcn_mfma_f32_16x16x32_bf16(pa[mi], vf[ni], ctx[mi][ni], 0, 0, 0);
            __builtin_amdgcn_sched_barrier(0);
        }
        __builtin_amdgcn_s_barrier();   // protect stage region + P before next subblock
        __builtin_amdgcn_sched_barrier(0);
    }

    // ---- rowsum partials: reduce over ch (8 lanes share a row) ----
    {
        float rsv0 = rs0, rsv1 = rs1, rsv2 = rs2, rsv3 = rs3;
#pragma unroll
        for (int o = 4; o > 0; o >>= 1) {
            rsv0 += __shfl_down(rsv0, o, 8);
            rsv1 += __shfl_down(rsv1, o, 8);
            rsv2 += __shfl_down(rsv2, o, 8);
            rsv3 += __shfl_down(rsv3, o, 8);
        }
        if (ch == 0) {
            rsumb[(size_t)mc * 6400 + bM + 0 * 16 + brow_r] = rsv0;
            rsumb[(size_t)mc * 6400 + bM + 1 * 16 + brow_r] = rsv1;
            rsumb[(size_t)mc * 6400 + bM + 2 * 16 + brow_r] = rsv2;
            rsumb[(size_t)mc * 6400 + bM + 3 * 16 + brow_r] = rsv3;
        }
    }

    // ---- ctx epilogue: [32][260] lt repack, f32 full-line stores ----
    float* lt = (float*)smem;
    float* Cf = partb + (size_t)mc * 1638400;
#pragma unroll
    for (int mi = 0; mi < 4; ++mi) {
        __syncthreads();
#pragma unroll
        for (int ni = 0; ni < 8; ++ni) {
            const int lcol = wn * 128 + ni * 16 + cl;
#pragma unroll
            for (int r = 0; r < 4; ++r)
                lt[(wm * 16 + g4 + r) * 260 + lcol] = ctx[mi][ni][r];
        }
        __syncthreads();
        const int grow = bM + mi * 16 + brow_r;
#pragma unroll
        for (int h = 0; h < 2; ++h) {
            const int gcol = h * 128 + ch * 16;
#pragma unroll
            for (int i = 0; i < 16; i += 4) {
                f32x4 q = *(const f32x4*)&lt[lr * 260 + gcol + i];
                *(f32x4*)&Cf[(size_t)grow * 256 + gcol + i] = q;
            }
        }
    }
}

// ---------------- softmax normalizer: inv[row] = 1 / sum_mc rsum[mc][row] ----------------
__global__ __launch_bounds__(256) void combine_inv(const float* __restrict__ rsum,
                                                   float* __restrict__ inv) {
    int r = blockIdx.x * 256 + threadIdx.x;   // 6400 rows
    float s = 0.f;
#pragma unroll
    for (int xb = 0; xb < 5; xb++) s += rsum[(size_t)xb * 6400 + r];
    inv[r] = 1.f / s;
}

// ---------------- reduce: ctxT bf16 = inv[row] * sum of 5 f32 partial chunks ----------------
__global__ __launch_bounds__(256) void reduce_ctx(const float* __restrict__ part, ushort* __restrict__ ctx,
                                                  const float* __restrict__ inv) {
    const size_t CH = 1638400;  // elems per chunk
    size_t i = ((size_t)blockIdx.x * 256 + threadIdx.x) * 4;
    float4 a = *(const float4*)&part[i];
#pragma unroll
    for (int c = 1; c < 5; c++) {
        float4 s = *(const float4*)&part[i + (size_t)c * CH];
        a.x += s.x; a.y += s.y; a.z += s.z; a.w += s.w;
    }
    const float w = inv[i >> 8];  // 256 cols per row
    uint2 o = { cvtpk(a.x * w, a.y * w), cvtpk(a.z * w, a.w * w) };
    *(uint2*)&ctx[i] = o;
}

// ---------------- host ----------------
extern "C" void kernel_launch(void* const* d_in, const int* in_sizes, int n_in,
                              void* d_out, int out_size, void* d_ws, size_t ws_size,
                              hipStream_t stream) {
    (void)in_sizes; (void)n_in; (void)out_size; (void)ws_size;
    const float* x     = (const float*)d_in[0];
    const float* wk    = (const float*)d_in[1];
    const float* bk    = (const float*)d_in[2];
    const float* gamma = (const float*)d_in[3];
    const float* beta  = (const float*)d_in[4];
    const float* rmean = (const float*)d_in[5];
    const float* rvar  = (const float*)d_in[6];
    const float* wv    = (const float*)d_in[7];
    const float* bv    = (const float*)d_in[8];
    const float* wW    = (const float*)d_in[9];
    const float* bW    = (const float*)d_in[10];
    float* out = (float*)d_out;

    // workspace layout (ushort elements)
    ushort* Xt   = (ushort*)d_ws;          // 2*6400*512   = 6,553,600
    ushort* wkb  = Xt + 6553600;           // 256*512      = 131,072
    ushort* wvb  = wkb + 131072;           // 131,072
    ushort* wWb  = wvb + 131072;           // 131,072
    ushort* Kt   = wWb + 131072;           // 2*6400*256   = 3,276,800
    ushort* V    = Kt + 3276800;           // 3,276,800
    ushort* ctxT = V + 3276800;            // 3,276,800
    float* scaleA = (float*)(ctxT + 3276800);
    float* shiftA = scaleA + 256;
    float* rowsum = shiftA + 256;          // 2*5*6400     = 64,000 f32
    float* inv    = rowsum + 64000;        // 6,400 f32
    float* part   = inv + 6400;            // 2*5*6400*256 f32 = 16,384,000 f32 (65.5 MB)
    // total ~100 MB

    cvt_f32_bf16<<<512, 256, 0, stream>>>(wk, wkb, 131072);
    cvt_f32_bf16<<<512, 256, 0, stream>>>(wv, wvb, 131072);
    cvt_f32_bf16<<<512, 256, 0, stream>>>(wW, wWb, 131072);
    prep_bn<<<1, 256, 0, stream>>>(bk, gamma, beta, rmean, rvar, scaleA, shiftA);
    transpose_cvt<<<dim3(200, 16, 2), dim3(32, 32), 0, stream>>>(x, Xt);

    // Kt[b][n][ck] = relu(affine(Xt . wk^T)), scaled by 0.25  — both batches in one dispatch
    gemm_nt<1><<<dim3(2, 50, 2), 256, 0, stream>>>(Xt, wkb, Kt, 512, 512, 512, 256,
                                                   3276800, 0, 1638400, scaleA, shiftA);
    // V[b][v][m] = wv . Xt^T + bv
    gemm_nt<2><<<dim3(50, 2, 2), 256, 0, stream>>>(wvb, Xt, V, 512, 512, 512, 6400,
                                                   0, 3276800, 1638400, bv, nullptr);

    // fused S+PV: both batches, all m-chunks in one dispatch (500 blocks)
    fused_spv<<<dim3(5, 50, 2), 256, 0, stream>>>(Kt, V, part, rowsum);

    for (int b = 0; b < 2; b++) {
        combine_inv<<<25, 256, 0, stream>>>(rowsum + (size_t)b * 32000, inv);
        reduce_ctx<<<1600, 256, 0, stream>>>(part + (size_t)b * 8192000,
                                             ctxT + (size_t)b * 1638400, inv);
    }

    // out[b][o][n] = wW . ctxT^T + bW  — both batches in one dispatch
    gemm_nt<3><<<dim3(50, 4, 2), 256, 0, stream>>>(wWb, ctxT, out, 256, 256, 256, 6400,
                                                   0, 1638400, 3276800, bW, nullptr);
}

// Round 11
// 311.584 us; speedup vs baseline: 1.0260x; 1.0030x over previous
//
#include <hip/hip_runtime.h>
#include <stdint.h>

typedef __attribute__((ext_vector_type(8))) short bf16x8;
typedef __attribute__((ext_vector_type(4))) float f32x4;

__device__ __forceinline__ ushort f2bf(float f) {
    union { float f; uint32_t i; } v; v.f = f;
    uint32_t r = v.i + 0x7fff + ((v.i >> 16) & 1);
    return (ushort)(r >> 16);
}
__device__ __forceinline__ uint32_t cvtpk(float lo, float hi) {
    uint32_t r;
    asm("v_cvt_pk_bf16_f32 %0, %1, %2" : "=v"(r) : "v"(lo), "v"(hi));
    return r;
}

typedef unsigned int uint_as1 __attribute__((address_space(1)));
typedef unsigned int uint_as3 __attribute__((address_space(3)));
__device__ __forceinline__ void async16(const void* g, void* l) {
    __builtin_amdgcn_global_load_lds((const uint_as1*)g, (uint_as3*)l, 16, 0, 0);
}

// ---------------- small prep kernels ----------------

__global__ void cvt_f32_bf16(const float* __restrict__ in, ushort* __restrict__ out, int n) {
    int i = blockIdx.x * blockDim.x + threadIdx.x;
    if (i < n) out[i] = f2bf(in[i]);
}

__global__ void prep_bn(const float* __restrict__ bk, const float* __restrict__ gamma,
                        const float* __restrict__ beta, const float* __restrict__ rmean,
                        const float* __restrict__ rvar,
                        float* __restrict__ scaleA, float* __restrict__ shiftA) {
    int i = threadIdx.x;  // 256 threads, 1 block
    float s = gamma[i] * rsqrtf(rvar[i] + 1e-5f);
    scaleA[i] = 0.25f * s;                                // fold Ck^-0.5 = 1/16 as 0.25 per operand
    shiftA[i] = 0.25f * ((bk[i] - rmean[i]) * s + beta[i]);
}

// x [b][512][6400] f32  ->  Xt [b][6400][512] bf16
__global__ void transpose_cvt(const float* __restrict__ x, ushort* __restrict__ xt) {
    __shared__ float t[32][33];
    int b = blockIdx.z;
    int n0 = blockIdx.x * 32, c0 = blockIdx.y * 32;
    const float* xb = x + (size_t)b * 512 * 6400;
    ushort* xtb = xt + (size_t)b * 6400 * 512;
    int tx = threadIdx.x, ty = threadIdx.y;
    t[ty][tx] = xb[(size_t)(c0 + ty) * 6400 + n0 + tx];
    __syncthreads();
    xtb[(size_t)(n0 + ty) * 512 + c0 + tx] = f2bf(t[tx][ty]);
}

// ---------------- unified NT GEMM: C[i][j] = sum_k A[i][k]*B[j][k] ----------------
// Round-6 proven core: 128x128 tile, 4 waves, BK=32, 3-buf LDS, counted vmcnt(4)
// + raw s_barrier per K-step. LDS quarter-swizzle (SQ_LDS_BANK_CONFLICT = 0).
// Epilogue repacks acc through LDS for full-line stores; bf16 via v_cvt_pk_bf16_f32.
// EPI 1: bf16 store relu(acc*vec0[col] + vec1[col])   (col-affine, BN+ReLU for Kt)
// EPI 2: bf16 store acc + vec0[row]                   (row bias, V)
// EPI 3: f32  store acc + vec0[row]                   (row bias, final out)
// EPI 4: f32  store raw                               (split-K partials, PV)
// EPI 6: SYMMETRIC exp tile (S = Kt.Kt^T is symmetric since q shares weights
//        with k): only blocks with bx >= by run; store exp(acc) tile AND its
//        mirror; rsum[bx][rows] from row sums, rsum[by][cols] from col sums
//        (mirror's row sums; skipped on diagonal). 49% of S K-loop work deleted.
template <int EPI>
__global__ __launch_bounds__(256) void gemm_nt(
    const ushort* __restrict__ A, const ushort* __restrict__ B, void* __restrict__ Cout,
    int K, int lda, int ldb, int ldc,
    size_t zsa, size_t zsb, size_t zsc,
    const float* __restrict__ vec0, const float* __restrict__ vec1,
    float* __restrict__ rsum) {
    if (EPI == 6 && blockIdx.x < blockIdx.y) return;   // lower triangle: no-op

    // [ A buf0|buf1|buf2 | B buf0|buf1|buf2 ], each 128x32 bf16 = 8 KB; total 48 KB
    __shared__ __align__(16) ushort smem[6 * 4096];

    A += (size_t)blockIdx.z * zsa;
    B += (size_t)blockIdx.z * zsb;

    const int tid = threadIdx.x;
    const int lane = tid & 63, wave = tid >> 6;
    const int wm = wave & 1, wn = wave >> 1;
    const int bM = blockIdx.y * 128, bN = blockIdx.x * 128;

    const int sr = lane >> 2;                              // row 0..15 within 16-row group
    const int scs = ((lane & 3) ^ ((lane >> 3) & 3)) * 8;  // swizzled source quarter
    const ushort* gA0 = A + (size_t)(bM + wave * 32 + sr) * lda + scs;
    const ushort* gA1 = gA0 + (size_t)16 * lda;
    const ushort* gB0 = B + (size_t)(bN + wave * 32 + sr) * ldb + scs;
    const ushort* gB1 = gB0 + (size_t)16 * ldb;
    ushort* lAw = &smem[wave * 1024];              // + buf*4096
    ushort* lBw = &smem[3 * 4096 + wave * 1024];   // + buf*4096

    const int rowA = wm * 64;
    const int rowB = wn * 64;
    const int fr = lane & 15;
    const int fk = ((lane >> 4) ^ ((fr >> 1) & 3)) * 8;   // swizzled quarter read

    f32x4 acc[4][4] = {};
    const int nT = K >> 5;

    auto stage = [&](int t, int buf) {
        const int k0 = t * 32;
        const int ob = buf * 4096;
        async16(gA0 + k0, lAw + ob);
        async16(gA1 + k0, lAw + ob + 512);
        async16(gB0 + k0, lBw + ob);
        async16(gB1 + k0, lBw + ob + 512);
    };

    stage(0, 0);
    if (nT > 1) stage(1, 1);

    for (int t = 0; t < nT; ++t) {
        if (t + 1 < nT) { asm volatile("s_waitcnt vmcnt(4)" ::: "memory"); }
        else            { asm volatile("s_waitcnt vmcnt(0)" ::: "memory"); }
        __builtin_amdgcn_sched_barrier(0);
        __builtin_amdgcn_s_barrier();
        __builtin_amdgcn_sched_barrier(0);
        if (t + 2 < nT) stage(t + 2, (t + 2) % 3);
        const int cur = t % 3;
        const ushort* lA = &smem[cur * 4096];
        const ushort* lB = &smem[3 * 4096 + cur * 4096];
        bf16x8 af[4], bff[4];
#pragma unroll
        for (int mi = 0; mi < 4; mi++)
            af[mi] = *(const bf16x8*)&lA[(rowA + mi * 16 + fr) * 32 + fk];
#pragma unroll
        for (int ni = 0; ni < 4; ni++)
            bff[ni] = *(const bf16x8*)&lB[(rowB + ni * 16 + fr) * 32 + fk];
#pragma unroll
        for (int mi = 0; mi < 4; mi++)
#pragma unroll
            for (int ni = 0; ni < 4; ni++)
                acc[mi][ni] = __builtin_amdgcn_mfma_f32_16x16x32_bf16(af[mi], bff[ni], acc[mi][ni], 0, 0, 0);
        __builtin_amdgcn_sched_barrier(0);
    }
    __builtin_amdgcn_s_barrier();
    __builtin_amdgcn_sched_barrier(0);

    // ---- epilogue: repack through LDS, store full lines ----
    float* Cf = (float*)Cout + (size_t)blockIdx.z * zsc;
    ushort* Cu = (ushort*)Cout + (size_t)blockIdx.z * zsc;
    float* lt = (float*)smem;          // 32*132*4 = 16896 B
    const int g4 = (lane >> 4) * 4;
    const int cl = lane & 15;
    const int lr = tid >> 3;           // reader: LDS row 0..31
    const int ch = tid & 7;            // reader: 16-col chunk 0..7

    if (EPI == 6) {
        const bool diag = (blockIdx.x == blockIdx.y);
        float creg[16];
#pragma unroll
        for (int i = 0; i < 16; i++) creg[i] = 0.f;
#pragma unroll
        for (int mi = 0; mi < 4; ++mi) {
#pragma unroll
            for (int ni = 0; ni < 4; ++ni) {
                const int lcol = wn * 64 + ni * 16 + cl;
#pragma unroll
                for (int r = 0; r < 4; ++r)
                    lt[(wm * 16 + g4 + r) * 132 + lcol] = acc[mi][ni][r];
            }
            __syncthreads();
            const int brow = (lr < 16) ? (mi * 16 + lr) : (64 + mi * 16 + (lr - 16));
            const int grow = bM + brow;
            const int gcol = bN + ch * 16;
            float vv[16];
#pragma unroll
            for (int i = 0; i < 16; i += 4) {
                f32x4 q = *(const f32x4*)&lt[lr * 132 + ch * 16 + i];
                vv[i] = __expf(q[0]); vv[i + 1] = __expf(q[1]);
                vv[i + 2] = __expf(q[2]); vv[i + 3] = __expf(q[3]);
            }
            float ssum = 0.f;
#pragma unroll
            for (int i = 0; i < 16; i++) { ssum += vv[i]; creg[i] += vv[i]; }
            ssum += __shfl_down(ssum, 4, 8);
            ssum += __shfl_down(ssum, 2, 8);
            ssum += __shfl_down(ssum, 1, 8);
            if (ch == 0) rsum[(size_t)blockIdx.x * 6400 + grow] = ssum;
            // direct tile store
            uint4 q0 = { cvtpk(vv[0], vv[1]), cvtpk(vv[2], vv[3]),
                         cvtpk(vv[4], vv[5]), cvtpk(vv[6], vv[7]) };
            uint4 q1 = { cvtpk(vv[8], vv[9]), cvtpk(vv[10], vv[11]),
                         cvtpk(vv[12], vv[13]), cvtpk(vv[14], vv[15]) };
            *(uint4*)&Cu[(size_t)grow * ldc + gcol] = q0;
            *(uint4*)&Cu[(size_t)grow * ldc + gcol + 8] = q1;
            if (!diag) {
                // write exp'd values back (each thread overwrites the cells it read)
#pragma unroll
                for (int i = 0; i < 16; i++) lt[lr * 132 + ch * 16 + i] = vv[i];
                __syncthreads();
                // mirror store: row j of mirror tile = col j of this strip
                const int j = tid >> 1, h = tid & 1;   // h: which 16-row run
                ushort mo[16];
#pragma unroll
                for (int i = 0; i < 16; i += 2) {
                    float a = lt[(h * 16 + i) * 132 + j];
                    float b2 = lt[(h * 16 + i + 1) * 132 + j];
                    *(uint32_t*)&mo[i] = cvtpk(a, b2);
                }
                const size_t mbase = (size_t)(bN + j) * ldc + bM + h * 64 + mi * 16;
                *(uint4*)&Cu[mbase] = *(const uint4*)&mo[0];
                *(uint4*)&Cu[mbase + 8] = *(const uint4*)&mo[8];
            }
            __syncthreads();
        }
        if (!diag) {
            // col sums (= mirror row sums) -> rsum slot by
#pragma unroll
            for (int i = 0; i < 16; i++) lt[lr * 132 + ch * 16 + i] = creg[i];
            __syncthreads();
            if (tid < 128) {
                float s = 0.f;
#pragma unroll
                for (int r = 0; r < 32; r++) s += lt[r * 132 + tid];
                rsum[(size_t)blockIdx.y * 6400 + bN + tid] = s;
            }
        }
        return;
    }

#pragma unroll
    for (int mi = 0; mi < 4; ++mi) {
#pragma unroll
        for (int ni = 0; ni < 4; ++ni) {
            const int lcol = wn * 64 + ni * 16 + cl;
#pragma unroll
            for (int r = 0; r < 4; ++r)
                lt[(wm * 16 + g4 + r) * 132 + lcol] = acc[mi][ni][r];
        }
        __syncthreads();
        {
            const int brow = (lr < 16) ? (mi * 16 + lr) : (64 + mi * 16 + (lr - 16));
            const int grow = bM + brow;
            const int gcol = bN + ch * 16;
            float vv[16];
#pragma unroll
            for (int i = 0; i < 16; i += 4) {
                f32x4 q = *(const f32x4*)&lt[lr * 132 + ch * 16 + i];
                vv[i] = q[0]; vv[i + 1] = q[1]; vv[i + 2] = q[2]; vv[i + 3] = q[3];
            }
            if (EPI == 1) {
#pragma unroll
                for (int i = 0; i < 16; i++)
                    vv[i] = fmaxf(vv[i] * vec0[gcol + i] + vec1[gcol + i], 0.f);
            }
            if (EPI == 2 || EPI == 3) {
                const float rb = vec0[grow];
#pragma unroll
                for (int i = 0; i < 16; i++) vv[i] += rb;
            }
            if (EPI == 3 || EPI == 4) {
#pragma unroll
                for (int i = 0; i < 16; i += 4) {
                    f32x4 q = { vv[i], vv[i + 1], vv[i + 2], vv[i + 3] };
                    *(f32x4*)&Cf[(size_t)grow * ldc + gcol + i] = q;
                }
            } else {
                uint4 q0 = { cvtpk(vv[0], vv[1]), cvtpk(vv[2], vv[3]),
                             cvtpk(vv[4], vv[5]), cvtpk(vv[6], vv[7]) };
                uint4 q1 = { cvtpk(vv[8], vv[9]), cvtpk(vv[10], vv[11]),
                             cvtpk(vv[12], vv[13]), cvtpk(vv[14], vv[15]) };
                *(uint4*)&Cu[(size_t)grow * ldc + gcol] = q0;
                *(uint4*)&Cu[(size_t)grow * ldc + gcol + 8] = q1;
            }
        }
        __syncthreads();
    }
}

// ---------------- softmax normalizer: inv[row] = 1 / sum_xb rsum[xb][row] ----------------
__global__ __launch_bounds__(256) void combine_inv(const float* __restrict__ rsum,
                                                   float* __restrict__ inv) {
    int r = blockIdx.x * 256 + threadIdx.x;   // 6400 rows
    float s = 0.f;
#pragma unroll
    for (int xb = 0; xb < 50; xb++) s += rsum[(size_t)xb * 6400 + r];
    inv[r] = 1.f / s;
}

// ---------------- split-K reduce: ctxT bf16 = inv[row] * sum of 5 f32 partial chunks ----------------
__global__ __launch_bounds__(256) void reduce_ctx(const float* __restrict__ part, ushort* __restrict__ ctx,
                                                  const float* __restrict__ inv) {
    const size_t CH = 1638400;  // elems per chunk
    size_t i = ((size_t)blockIdx.x * 256 + threadIdx.x) * 4;
    float4 a = *(const float4*)&part[i];
#pragma unroll
    for (int c = 1; c < 5; c++) {
        float4 s = *(const float4*)&part[i + (size_t)c * CH];
        a.x += s.x; a.y += s.y; a.z += s.z; a.w += s.w;
    }
    const float w = inv[i >> 8];  // 256 cols per row; 4 consecutive elems share a row
    uint2 o = { cvtpk(a.x * w, a.y * w), cvtpk(a.z * w, a.w * w) };
    *(uint2*)&ctx[i] = o;
}

// ---------------- host ----------------
extern "C" void kernel_launch(void* const* d_in, const int* in_sizes, int n_in,
                              void* d_out, int out_size, void* d_ws, size_t ws_size,
                              hipStream_t stream) {
    (void)in_sizes; (void)n_in; (void)out_size; (void)ws_size;
    const float* x     = (const float*)d_in[0];
    const float* wk    = (const float*)d_in[1];
    const float* bk    = (const float*)d_in[2];
    const float* gamma = (const float*)d_in[3];
    const float* beta  = (const float*)d_in[4];
    const float* rmean = (const float*)d_in[5];
    const float* rvar  = (const float*)d_in[6];
    const float* wv    = (const float*)d_in[7];
    const float* bv    = (const float*)d_in[8];
    const float* wW    = (const float*)d_in[9];
    const float* bW    = (const float*)d_in[10];
    float* out = (float*)d_out;

    // workspace layout (ushort elements)
    ushort* Xt   = (ushort*)d_ws;          // 2*6400*512   = 6,553,600
    ushort* wkb  = Xt + 6553600;           // 256*512      = 131,072
    ushort* wvb  = wkb + 131072;           // 131,072
    ushort* wWb  = wvb + 131072;           // 131,072
    ushort* Kt   = wWb + 131072;           // 2*6400*256   = 3,276,800
    ushort* V    = Kt + 3276800;           // 3,276,800
    ushort* ctxT = V + 3276800;            // 3,276,800
    ushort* S    = ctxT + 3276800;         // 6400*6400    = 40,960,000 (one batch, reused)
    float* scaleA = (float*)(S + 40960000);
    float* shiftA = scaleA + 256;
    float* rowsum = shiftA + 256;          // 50*6400      = 320,000 f32
    float* inv    = rowsum + 320000;       // 6400 f32
    float* part   = inv + 6400;            // 5*6400*256 f32 = 8,192,000 f32 (33 MB)
    // total ~150 MB

    cvt_f32_bf16<<<512, 256, 0, stream>>>(wk, wkb, 131072);
    cvt_f32_bf16<<<512, 256, 0, stream>>>(wv, wvb, 131072);
    cvt_f32_bf16<<<512, 256, 0, stream>>>(wW, wWb, 131072);
    prep_bn<<<1, 256, 0, stream>>>(bk, gamma, beta, rmean, rvar, scaleA, shiftA);
    transpose_cvt<<<dim3(200, 16, 2), dim3(32, 32), 0, stream>>>(x, Xt);

    // Kt[b][n][ck] = relu(affine(Xt . wk^T)), scaled by 0.25  — both batches in one dispatch
    gemm_nt<1><<<dim3(2, 50, 2), 256, 0, stream>>>(Xt, wkb, Kt, 512, 512, 512, 256,
                                                   3276800, 0, 1638400, scaleA, shiftA, nullptr);
    // V[b][v][m] = wv . Xt^T + bv
    gemm_nt<2><<<dim3(50, 2, 2), 256, 0, stream>>>(wvb, Xt, V, 512, 512, 512, 6400,
                                                   0, 3276800, 1638400, bv, nullptr, nullptr);

    for (int b = 0; b < 2; b++) {
        ushort* Ktb  = Kt + (size_t)b * 1638400;
        ushort* Vb   = V  + (size_t)b * 1638400;
        ushort* ctxb = ctxT + (size_t)b * 1638400;
        // P_unnorm = exp(Kt . Kt^T), SYMMETRIC: upper-triangle blocks only,
        // mirrored stores + dual rowsum partials
        gemm_nt<6><<<dim3(50, 50), 256, 0, stream>>>(Ktb, Ktb, S, 256, 256, 256, 6400,
                                                     0, 0, 0, nullptr, nullptr, rowsum);
        combine_inv<<<25, 256, 0, stream>>>(rowsum, inv);
        // ctxT[n][v] = P_unnorm . V^T — split-K x5 into f32 partials (z = k-chunk of 1280)
        gemm_nt<4><<<dim3(2, 50, 5), 256, 0, stream>>>(S, Vb, part, 1280, 6400, 6400, 256,
                                                       1280, 1280, 1638400, nullptr, nullptr, nullptr);
        reduce_ctx<<<1600, 256, 0, stream>>>(part, ctxb, inv);
    }

    // out[b][o][n] = wW . ctxT^T + bW  — both batches in one dispatch
    gemm_nt<3><<<dim3(50, 4, 2), 256, 0, stream>>>(wWb, ctxT, out, 256, 256, 256, 6400,
                                                   0, 1638400, 3276800, bW, nullptr, nullptr);
}